// Round 7
// baseline (343.338 us; speedup 1.0000x reference)
//
#include <hip/hip_runtime.h>
#include <hip/hip_bf16.h>

// B=64, I=2048, D=8, O=32, K=16, E=O*K=512.
// pass: 512 blocks (one per 4-i chunk), 512 thr = 8 waves.
//   wave w: iq=w>>1 (i-slot 0..3), q=w&1 (k-octet); lane: o=l&31, kk=l>>5.
//   kg = q*2+kk -> per-thread k's = kg*4+j (j<4); Wr = W[i][o][:][4k] = 32 regs.
// part[b][ch][e] bf16, e = k*32+o.
// reduce: 256 blocks (b x ch-quarter) -> atomicAdd s2 -> last block squashes.

__device__ __forceinline__ float4 f4add(float4 a, float4 b) {
    return make_float4(a.x + b.x, a.y + b.y, a.z + b.z, a.w + b.w);
}

template<int PASS0>
__global__ __launch_bounds__(512, 4)   // 2 blocks/CU, 128-VGPR cap
void pass_kernel(const float* __restrict__ x,            // [64][2048][8]
                 const float* __restrict__ W,            // [2048][32][8][16]
                 const float* __restrict__ vin,          // [64][512] e-layout
                 unsigned short* __restrict__ part)      // [64][512][512] bf16
{
    __shared__ __align__(16) float x_lds[2048];   //  8 KB: [b][iq*8+d]
    __shared__ __align__(16) float red[8 * 512];  // 16 KB: [iq*2+bq][e]
    __shared__ __align__(16) float vg[2 * 512];   //  4 KB: [bq][e]
    __shared__ float lred[512];                   //  2 KB: [((q*4+iq)*2+bq)*32+o]

    const int t  = threadIdx.x;
    const int w  = t >> 6, l = t & 63;
    const int iq = w >> 1, q = w & 1;
    const int o  = l & 31, kk = l >> 5;
    const int kg = q * 2 + kk;
    const int ch = blockIdx.x;
    const int i  = ch * 4 + iq;

    // ---- W[i][o][d][kg*4..+4] -> 32 registers (pinned; ample headroom now) --
    float Wr[8][4];
    {
        const float* wp = W + (size_t)(i * 32 + o) * 128 + kg * 4;
        #pragma unroll
        for (int d = 0; d < 8; ++d) {
            float4 a = *(const float4*)(wp + d * 16);
            Wr[d][0] = a.x; Wr[d][1] = a.y; Wr[d][2] = a.z; Wr[d][3] = a.w;
        }
        #pragma unroll
        for (int d = 0; d < 8; ++d)
            #pragma unroll
            for (int j = 0; j < 4; ++j)
                asm volatile("" : "+v"(Wr[d][j]));
    }
    // ---- stage x[:, ch*4..+4, :]: 2048 floats, one float4/thread ------------
    {
        const int f = t * 4, b = f >> 5, r = f & 31;
        *(float4*)&x_lds[f] = *(const float4*)(x + (size_t)b * 16384 + ch * 32 + r);
    }

    for (int g = 0; g < 32; ++g) {       // 2 b's per group
        if (!PASS0) {
            if (t < 256) {               // stage vsum for the group's 2 b's
                const int bq = t >> 7, idx = t & 127;
                *(float4*)&vg[bq * 512 + idx * 4] =
                    *(const float4*)(vin + (size_t)(g * 2 + bq) * 512 + idx * 4);
            }
        }
        __syncthreads();                 // A: vg/x ready; red safe to rewrite

        float uh[2][4]; float lp[2];
        #pragma unroll
        for (int bq = 0; bq < 2; ++bq) {
            const int b = g * 2 + bq;
            float4 xa = *(const float4*)&x_lds[b * 32 + iq * 8];
            float4 xb = *(const float4*)&x_lds[b * 32 + iq * 8 + 4];
            float xr[8] = {xa.x, xa.y, xa.z, xa.w, xb.x, xb.y, xb.z, xb.w};
            #pragma unroll
            for (int j = 0; j < 4; ++j) uh[bq][j] = 0.f;
            #pragma unroll
            for (int d = 0; d < 8; ++d)
                #pragma unroll
                for (int j = 0; j < 4; ++j)
                    uh[bq][j] = fmaf(xr[d], Wr[d][j], uh[bq][j]);
            if (!PASS0) {
                float s = 0.f;
                #pragma unroll
                for (int j = 0; j < 4; ++j)
                    s = fmaf(uh[bq][j], vg[bq * 512 + (kg * 4 + j) * 32 + o], s);
                s += __shfl_xor(s, 32, 64);          // combine kk within wave
                lp[bq] = s;                           // = this q-octet's partial
                if (kk == 0) lred[((q * 4 + iq) * 2 + bq) * 32 + o] = s;
            }
        }
        if (!PASS0) __syncthreads();     // B: lred ready (cross-wave-pair)

        #pragma unroll
        for (int bq = 0; bq < 2; ++bq) {
            float c;
            if (PASS0) {
                c = 0.03125f;            // softmax of zeros
            } else {
                float logit = lp[bq] + lred[(((q ^ 1) * 4 + iq) * 2 + bq) * 32 + o];
                float ex = __expf(logit);            // |logit| small: no max
                float sm = ex;
                #pragma unroll
                for (int off = 16; off >= 1; off >>= 1)
                    sm += __shfl_xor(sm, off, 64);   // denom over 32 o's
                c = __fdividef(ex, sm);
            }
            #pragma unroll
            for (int j = 0; j < 4; ++j)              // bank=o, 2-way(kk): free
                red[(iq * 2 + bq) * 512 + (kg * 4 + j) * 32 + o] = c * uh[bq][j];
        }
        __syncthreads();                 // C: red complete

        if (t < 256) {                   // fold 4 i-slots -> bf16 chunk partial
            const int bq = t >> 7, e4 = (t & 127) * 4;
            float4 s = make_float4(0.f, 0.f, 0.f, 0.f);
            #pragma unroll
            for (int q2 = 0; q2 < 4; ++q2)
                s = f4add(s, *(const float4*)&red[(q2 * 2 + bq) * 512 + e4]);
            __hip_bfloat16 h0 = __float2bfloat16(s.x), h1 = __float2bfloat16(s.y);
            __hip_bfloat16 h2 = __float2bfloat16(s.z), h3 = __float2bfloat16(s.w);
            ushort4 u;
            u.x = *(unsigned short*)&h0; u.y = *(unsigned short*)&h1;
            u.z = *(unsigned short*)&h2; u.w = *(unsigned short*)&h3;
            const int b = g * 2 + bq;
            *(ushort4*)(part + ((size_t)b * 512 + ch) * 512 + e4) = u;
        }
        // no trailing barrier: next group's A separates fold reads / red writes
    }
}

// ---------------------------------------------------------------------------
// reduce: 256 blocks = (b 64) x (qc 4). Sum 128 chunks -> atomicAdd into
// s2[b][e]; last-arriving block per b re-reads coherently, applies per-(b,o)
// squash, updates vsum (PHASE 0/1) or writes out (PHASE 2).
// ---------------------------------------------------------------------------
template<int PHASE>
__global__ __launch_bounds__(512)
void reduce_kernel(const unsigned short* __restrict__ part,
                   float* __restrict__ s2, int* __restrict__ cnt,
                   float* __restrict__ vsum, float* __restrict__ out)
{
    __shared__ float wpart[8][32];
    __shared__ int amLast;
    const int b = blockIdx.x >> 2, qc = blockIdx.x & 3;
    const int t = threadIdx.x;
    const int hh = t >> 8, ee = (t & 255) * 2;

    const unsigned short* base = part + ((size_t)b * 512 + qc * 128) * 512;
    float a0 = 0.f, a1 = 0.f;
    #pragma unroll 4
    for (int it = 0; it < 64; ++it) {
        const int row = it * 2 + hh;
        ushort2 u = *(const ushort2*)(base + (size_t)row * 512 + ee);
        a0 += __uint_as_float((unsigned)u.x << 16);
        a1 += __uint_as_float((unsigned)u.y << 16);
    }
    atomicAdd(&s2[(size_t)b * 512 + ee],     a0);
    atomicAdd(&s2[(size_t)b * 512 + ee + 1], a1);
    __threadfence();
    __syncthreads();
    if (t == 0) amLast = (atomicAdd(&cnt[b], 1) == 3);
    __syncthreads();

    if (amLast) {
        float s = atomicAdd(&s2[(size_t)b * 512 + t], 0.f);   // coherent read
        float sq = s * s;
        sq += __shfl_xor(sq, 32, 64);            // pair the wave's 2 k's
        if ((t & 63) < 32) wpart[t >> 6][t & 31] = sq;
        __syncthreads();
        float n2 = 0.f;
        #pragma unroll
        for (int ww = 0; ww < 8; ++ww) n2 += wpart[ww][t & 31];   // over 16 k
        float v = n2 / (1.f + n2) * rsqrtf(n2 + 1e-7f) * s;
        if (PHASE == 2)
            out[(size_t)b * 512 + (t & 31) * 16 + (t >> 5)] = v;  // [b][o][k]
        else if (PHASE == 1)
            vsum[(size_t)b * 512 + t] += v;
        else
            vsum[(size_t)b * 512 + t] = v;
    }
}

// ---------------------------------------------------------------------------
extern "C" void kernel_launch(void* const* d_in, const int* in_sizes, int n_in,
                              void* d_out, int out_size, void* d_ws, size_t ws_size,
                              hipStream_t stream)
{
    const float* x = (const float*)d_in[0];
    const float* W = (const float*)d_in[1];
    float* out = (float*)d_out;
    char* ws = (char*)d_ws;

    const size_t partB = (size_t)64 * 512 * 512 * 2;   // 32 MB bf16
    const size_t s2B   = (size_t)3 * 64 * 512 * 4;     // 384 KB
    const size_t cntB  = 1024;                         // 3*64 ints, padded
    const size_t vsumB = (size_t)64 * 512 * 4;         // 128 KB
    if (ws_size < partB + s2B + cntB + vsumB) return;  // needs ~32.5 MB

    unsigned short* part = (unsigned short*)ws;
    float* s2   = (float*)(ws + partB);
    int*   cnt  = (int*)(ws + partB + s2B);
    float* vsum = (float*)(ws + partB + s2B + cntB);

    hipMemsetAsync(s2, 0, s2B + cntB, stream);         // zero accum + tickets

    // round 0: c uniform -> v0; vsum = v0
    pass_kernel<1><<<512, 512, 0, stream>>>(x, W, vsum, part);
    reduce_kernel<0><<<256, 512, 0, stream>>>(part, s2,            cnt,       vsum, out);
    // round 1: logits = u_hat . v0 -> v1; vsum = v0 + v1
    pass_kernel<0><<<512, 512, 0, stream>>>(x, W, vsum, part);
    reduce_kernel<1><<<256, 512, 0, stream>>>(part, s2 + 64 * 512, cnt + 64,  vsum, out);
    // round 2: logits = u_hat . (v0+v1) -> v2 = output
    pass_kernel<0><<<512, 512, 0, stream>>>(x, W, vsum, part);
    reduce_kernel<2><<<256, 512, 0, stream>>>(part, s2 + 2 * 64 * 512, cnt + 128, vsum, out);
}

// Round 10
// 256.769 us; speedup vs baseline: 1.3371x; 1.3371x over previous
//
#include <hip/hip_runtime.h>

// B=64, I=2048, D=8, O=32, K=16.
// pass grid: 512 blocks = (h = bx>>8: b-half) x (ch = bx&255: 8-i chunk).
// Thread map: wave w = i-slot (8 i/chunk); lane l: o = l&31, kk = l>>5 (k-half).
// Per-thread W = W[i][o][:][kk*8..+8] = 64 floats, register-resident via
// waves_per_eu(2,2) (R4 evidence: the only config that held W at VGPR=100).
// part[b][ch][e], e = k*32+o (transposed so reduce1 streams contiguously).
// R10 fix: reduce1 quarters are 64 chunks (R8/R9 used 128 -> read b+1's rows).

__device__ __forceinline__ float4 f4add(float4 a, float4 b) {
    return make_float4(a.x + b.x, a.y + b.y, a.z + b.z, a.w + b.w);
}

template<int PASS0>
__global__ __launch_bounds__(512)
__attribute__((amdgpu_waves_per_eu(2, 2)))   // min=max: allocator keeps Wr live
void pass_kernel(const float* __restrict__ x,    // [64][2048][8]
                 const float* __restrict__ W,    // [2048][32][8][16]
                 const float* __restrict__ vin,  // [64][512] e-layout
                 float* __restrict__ part)       // [64][256][512]
{
    __shared__ __align__(16) float x_lds[32 * 64];   //  8 KB: [bl][il*8+d]
    __shared__ __align__(16) float red[8 * 2 * 512]; // 32 KB: [w*2+bq][e]
    __shared__ __align__(16) float vg[2 * 512];      //  4 KB: [bq][e]

    const int t  = threadIdx.x;
    const int w  = t >> 6;
    const int l  = t & 63;
    const int o  = l & 31;
    const int kk = l >> 5;
    const int bx = blockIdx.x;
    const int ch = bx & 255;
    const int h  = bx >> 8;          // b-half: b in [h*32, h*32+32)
    const int i  = ch * 8 + w;

    // ---- W[i][o][d][kk-half] -> 64 registers -------------------------------
    float Wr[8][8];
    {
        const float* wp = W + (size_t)(i * 32 + o) * 128 + kk * 8;
        #pragma unroll
        for (int d = 0; d < 8; ++d) {
            float4 a = *(const float4*)(wp + d * 16);
            float4 b = *(const float4*)(wp + d * 16 + 4);
            Wr[d][0] = a.x; Wr[d][1] = a.y; Wr[d][2] = a.z; Wr[d][3] = a.w;
            Wr[d][4] = b.x; Wr[d][5] = b.y; Wr[d][6] = b.z; Wr[d][7] = b.w;
        }
        #pragma unroll
        for (int d = 0; d < 8; ++d)
            #pragma unroll
            for (int j = 0; j < 8; ++j)
                asm volatile("" : "+v"(Wr[d][j]));   // discourage remat
    }
    // ---- stage x[h-half, chunk, :]: 2048 floats, one float4/thread ---------
    {
        const int f  = t * 4;
        const int bl = f >> 6, r = f & 63;
        *(float4*)&x_lds[f] =
            *(const float4*)(x + (size_t)(h * 32 + bl) * 16384 + ch * 64 + r);
    }

    for (int g = 0; g < 16; ++g) {       // 2 b's per group
        if (!PASS0) {
            if (t < 256) {               // stage vsum for the group's 2 b's
                const int bq = t >> 7, idx = t & 127;
                const int b  = h * 32 + g * 2 + bq;
                *(float4*)&vg[bq * 512 + idx * 4] =
                    *(const float4*)(vin + (size_t)b * 512 + idx * 4);
            }
        }
        __syncthreads();                 // vg ready (and x_lds/red safe)

        #pragma unroll
        for (int bq = 0; bq < 2; ++bq) {
            const int bl = g * 2 + bq;
            float4 xa = *(const float4*)&x_lds[bl * 64 + w * 8];
            float4 xb = *(const float4*)&x_lds[bl * 64 + w * 8 + 4];
            float xr[8] = {xa.x, xa.y, xa.z, xa.w, xb.x, xb.y, xb.z, xb.w};
            float uh[8];
            #pragma unroll
            for (int j = 0; j < 8; ++j) uh[j] = 0.f;
            #pragma unroll
            for (int d = 0; d < 8; ++d) {
                #pragma unroll
                for (int j = 0; j < 8; ++j)
                    uh[j] = fmaf(xr[d], Wr[d][j], uh[j]);
            }
            float c;
            if (PASS0) {
                c = 0.03125f;            // softmax of zeros
            } else {
                float logit = 0.f;
                #pragma unroll
                for (int j = 0; j < 8; ++j)
                    logit = fmaf(uh[j], vg[bq * 512 + (kk * 8 + j) * 32 + o], logit);
                logit += __shfl_xor(logit, 32, 64);   // combine k-halves
                float ex = __expf(logit);             // |logit| small: no max
                float sm = ex;
                #pragma unroll
                for (int off = 16; off >= 1; off >>= 1)
                    sm += __shfl_xor(sm, off, 64);    // denom over 32 o's
                c = __fdividef(ex, sm);
            }
            #pragma unroll
            for (int j = 0; j < 8; ++j)               // bank=o, 2-way(kk): free
                red[(w * 2 + bq) * 512 + (kk * 8 + j) * 32 + o] = c * uh[j];
        }
        __syncthreads();                 // red complete

        if (t < 256) {                   // fold 8 i-slots -> per-chunk partial
            const int bq = t >> 7, e4 = (t & 127) * 4;
            float4 s = make_float4(0.f, 0.f, 0.f, 0.f);
            #pragma unroll
            for (int slot = 0; slot < 8; ++slot)
                s = f4add(s, *(const float4*)&red[(slot * 2 + bq) * 512 + e4]);
            const int b = h * 32 + g * 2 + bq;
            *(float4*)(part + ((size_t)b * 256 + ch) * 512 + e4) = s;
        }
        // no trailing barrier: next group's first barrier orders red/vg reuse
    }
}

// ---------------------------------------------------------------------------
// reduce1: 256 blocks = (b = bx>>2) x (qc = bx&3). Each streams 64 rows of
// part[b][qc*64..qc*64+63][e] (contiguous 128 KB) into part2[b][qc][e].
// (4 quarters x 64 = 256 chunks, each counted exactly once.)
// ---------------------------------------------------------------------------
__global__ __launch_bounds__(128)
void reduce1(const float* __restrict__ part, float* __restrict__ part2)
{
    const int b = blockIdx.x >> 2, qc = blockIdx.x & 3;
    const int t = threadIdx.x;
    const float* p0 = part + ((size_t)b * 256 + qc * 64) * 512 + t * 4;
    float4 acc = make_float4(0.f, 0.f, 0.f, 0.f);
    #pragma unroll 4
    for (int r = 0; r < 64; ++r)
        acc = f4add(acc, *(const float4*)(p0 + (size_t)r * 512));
    *(float4*)(part2 + ((size_t)b * 4 + qc) * 512 + t * 4) = acc;
}

// ---------------------------------------------------------------------------
// reduce2: fold 4 partials, per-(b,o) squash (R6-proven wpart mapping for
// e = k*32+o), update vsum (PHASE 0/1) or write out[b][o][k] (PHASE 2).
// ---------------------------------------------------------------------------
template<int PHASE>
__global__ __launch_bounds__(512)
void reduce2(const float* __restrict__ part2, float* __restrict__ vsum,
             float* __restrict__ out)
{
    __shared__ float wpart[8][32];
    const int b = blockIdx.x, t = threadIdx.x;
    float s = 0.f;
    #pragma unroll
    for (int qc = 0; qc < 4; ++qc)
        s += part2[((size_t)b * 4 + qc) * 512 + t];
    float sq = s * s;
    sq += __shfl_xor(sq, 32, 64);              // pair the wave's 2 k's
    if ((t & 63) < 32) wpart[t >> 6][t & 31] = sq;
    __syncthreads();
    float n2 = 0.f;
    #pragma unroll
    for (int ww = 0; ww < 8; ++ww) n2 += wpart[ww][t & 31];   // over 16 k
    float v = n2 / (1.f + n2) * rsqrtf(n2 + 1e-7f) * s;
    if (PHASE == 2)
        out[(size_t)b * 512 + (t & 31) * 16 + (t >> 5)] = v;  // [b][o][k]
    else if (PHASE == 1)
        vsum[(size_t)b * 512 + t] += v;
    else
        vsum[(size_t)b * 512 + t] = v;
}

// ---------------------------------------------------------------------------
extern "C" void kernel_launch(void* const* d_in, const int* in_sizes, int n_in,
                              void* d_out, int out_size, void* d_ws, size_t ws_size,
                              hipStream_t stream)
{
    const float* x = (const float*)d_in[0];
    const float* W = (const float*)d_in[1];
    float* out = (float*)d_out;
    char* ws = (char*)d_ws;

    const size_t partB  = (size_t)64 * 256 * 512 * 4;  // 32 MB
    const size_t part2B = (size_t)64 * 4 * 512 * 4;    // 512 KB
    const size_t vsumB  = (size_t)64 * 512 * 4;        // 128 KB
    if (ws_size < partB + part2B + vsumB) return;      // 32.625 MB (R6-proven)

    float* part  = (float*)ws;
    float* part2 = (float*)(ws + partB);
    float* vsum  = (float*)(ws + partB + part2B);

    // round 0: c uniform -> v0; vsum = v0
    pass_kernel<1><<<512, 512, 0, stream>>>(x, W, vsum, part);
    reduce1<<<256, 128, 0, stream>>>(part, part2);
    reduce2<0><<<64, 512, 0, stream>>>(part2, vsum, out);
    // round 1: logits = u_hat . v0 -> v1; vsum = v0 + v1
    pass_kernel<0><<<512, 512, 0, stream>>>(x, W, vsum, part);
    reduce1<<<256, 128, 0, stream>>>(part, part2);
    reduce2<1><<<64, 512, 0, stream>>>(part2, vsum, out);
    // round 2: logits = u_hat . (v0+v1) -> v2 = output
    pass_kernel<0><<<512, 512, 0, stream>>>(x, W, vsum, part);
    reduce1<<<256, 128, 0, stream>>>(part, part2);
    reduce2<2><<<64, 512, 0, stream>>>(part2, vsum, out);
}

// Round 11
// 208.901 us; speedup vs baseline: 1.6435x; 1.2291x over previous
//
#include <hip/hip_runtime.h>

// B=64, I=2048, D=8, O=32, K=16.
// pass grid: 512 blocks = (h = bx>>8: b-half) x (ch = bx&255: 8-i chunk).
// Thread map: wave w = i-slot (8 i/chunk); lane l: o = l&31, kk = l>>5 (k-half).
// Per-thread W = W[i][o][:][kk*8..+8] = 64 floats, register-resident.
// R11 experiment: waves_per_eu(4,4) — min=max blocks occupancy-driven W
// eviction (R7/R5 failure), 128-VGPR cap fits 64 Wr + ~45 working (R10's
// (2,2) held W but starved latency hiding at 8 waves/CU -> 66 us).
// part[b][ch][e], e = k*32+o (transposed so reduce1 streams contiguously).

__device__ __forceinline__ float4 f4add(float4 a, float4 b) {
    return make_float4(a.x + b.x, a.y + b.y, a.z + b.z, a.w + b.w);
}

template<int PASS0>
__global__ __launch_bounds__(512)
__attribute__((amdgpu_waves_per_eu(4, 4)))   // min=max, 128-VGPR budget
void pass_kernel(const float* __restrict__ x,    // [64][2048][8]
                 const float* __restrict__ W,    // [2048][32][8][16]
                 const float* __restrict__ vin,  // [64][512] e-layout
                 float* __restrict__ part)       // [64][256][512]
{
    __shared__ __align__(16) float x_lds[32 * 64];   //  8 KB: [bl][il*8+d]
    __shared__ __align__(16) float red[8 * 2 * 512]; // 32 KB: [w*2+bq][e]
    __shared__ __align__(16) float vg[2 * 512];      //  4 KB: [bq][e]

    const int t  = threadIdx.x;
    const int w  = t >> 6;
    const int l  = t & 63;
    const int o  = l & 31;
    const int kk = l >> 5;
    const int bx = blockIdx.x;
    const int ch = bx & 255;
    const int h  = bx >> 8;          // b-half: b in [h*32, h*32+32)
    const int i  = ch * 8 + w;

    // ---- W[i][o][d][kk-half] -> 64 registers -------------------------------
    float Wr[8][8];
    {
        const float* wp = W + (size_t)(i * 32 + o) * 128 + kk * 8;
        #pragma unroll
        for (int d = 0; d < 8; ++d) {
            float4 a = *(const float4*)(wp + d * 16);
            float4 b = *(const float4*)(wp + d * 16 + 4);
            Wr[d][0] = a.x; Wr[d][1] = a.y; Wr[d][2] = a.z; Wr[d][3] = a.w;
            Wr[d][4] = b.x; Wr[d][5] = b.y; Wr[d][6] = b.z; Wr[d][7] = b.w;
        }
        #pragma unroll
        for (int d = 0; d < 8; ++d)
            #pragma unroll
            for (int j = 0; j < 8; ++j)
                asm volatile("" : "+v"(Wr[d][j]));   // discourage remat
    }
    // ---- stage x[h-half, chunk, :]: 2048 floats, one float4/thread ---------
    {
        const int f  = t * 4;
        const int bl = f >> 6, r = f & 63;
        *(float4*)&x_lds[f] =
            *(const float4*)(x + (size_t)(h * 32 + bl) * 16384 + ch * 64 + r);
    }

    for (int g = 0; g < 16; ++g) {       // 2 b's per group
        if (!PASS0) {
            if (t < 256) {               // stage vsum for the group's 2 b's
                const int bq = t >> 7, idx = t & 127;
                const int b  = h * 32 + g * 2 + bq;
                *(float4*)&vg[bq * 512 + idx * 4] =
                    *(const float4*)(vin + (size_t)b * 512 + idx * 4);
            }
        }
        __syncthreads();                 // vg ready (and x_lds/red safe)

        #pragma unroll
        for (int bq = 0; bq < 2; ++bq) {
            const int bl = g * 2 + bq;
            float4 xa = *(const float4*)&x_lds[bl * 64 + w * 8];
            float4 xb = *(const float4*)&x_lds[bl * 64 + w * 8 + 4];
            float xr[8] = {xa.x, xa.y, xa.z, xa.w, xb.x, xb.y, xb.z, xb.w};
            float uh[8];
            #pragma unroll
            for (int j = 0; j < 8; ++j) uh[j] = 0.f;
            #pragma unroll
            for (int d = 0; d < 8; ++d) {
                #pragma unroll
                for (int j = 0; j < 8; ++j)
                    uh[j] = fmaf(xr[d], Wr[d][j], uh[j]);
            }
            float c;
            if (PASS0) {
                c = 0.03125f;            // softmax of zeros
            } else {
                float logit = 0.f;
                #pragma unroll
                for (int j = 0; j < 8; ++j)
                    logit = fmaf(uh[j], vg[bq * 512 + (kk * 8 + j) * 32 + o], logit);
                logit += __shfl_xor(logit, 32, 64);   // combine k-halves
                float ex = __expf(logit);             // |logit| small: no max
                float sm = ex;
                #pragma unroll
                for (int off = 16; off >= 1; off >>= 1)
                    sm += __shfl_xor(sm, off, 64);    // denom over 32 o's
                c = __fdividef(ex, sm);
            }
            #pragma unroll
            for (int j = 0; j < 8; ++j)               // bank=o, 2-way(kk): free
                red[(w * 2 + bq) * 512 + (kk * 8 + j) * 32 + o] = c * uh[j];
        }
        __syncthreads();                 // red complete

        if (t < 256) {                   // fold 8 i-slots -> per-chunk partial
            const int bq = t >> 7, e4 = (t & 127) * 4;
            float4 s = make_float4(0.f, 0.f, 0.f, 0.f);
            #pragma unroll
            for (int slot = 0; slot < 8; ++slot)
                s = f4add(s, *(const float4*)&red[(slot * 2 + bq) * 512 + e4]);
            const int b = h * 32 + g * 2 + bq;
            *(float4*)(part + ((size_t)b * 256 + ch) * 512 + e4) = s;
        }
        // no trailing barrier: next group's first barrier orders red/vg reuse
    }
}

// ---------------------------------------------------------------------------
// reduce1: 256 blocks = (b = bx>>2) x (qc = bx&3). Each streams 64 rows of
// part[b][qc*64..qc*64+63][e] (contiguous 128 KB) into part2[b][qc][e].
// ---------------------------------------------------------------------------
__global__ __launch_bounds__(128)
void reduce1(const float* __restrict__ part, float* __restrict__ part2)
{
    const int b = blockIdx.x >> 2, qc = blockIdx.x & 3;
    const int t = threadIdx.x;
    const float* p0 = part + ((size_t)b * 256 + qc * 64) * 512 + t * 4;
    float4 acc = make_float4(0.f, 0.f, 0.f, 0.f);
    #pragma unroll 4
    for (int r = 0; r < 64; ++r)
        acc = f4add(acc, *(const float4*)(p0 + (size_t)r * 512));
    *(float4*)(part2 + ((size_t)b * 4 + qc) * 512 + t * 4) = acc;
}

// ---------------------------------------------------------------------------
// reduce2: fold 4 partials, per-(b,o) squash (R6-proven wpart mapping for
// e = k*32+o), update vsum (PHASE 0/1) or write out[b][o][k] (PHASE 2).
// ---------------------------------------------------------------------------
template<int PHASE>
__global__ __launch_bounds__(512)
void reduce2(const float* __restrict__ part2, float* __restrict__ vsum,
             float* __restrict__ out)
{
    __shared__ float wpart[8][32];
    const int b = blockIdx.x, t = threadIdx.x;
    float s = 0.f;
    #pragma unroll
    for (int qc = 0; qc < 4; ++qc)
        s += part2[((size_t)b * 4 + qc) * 512 + t];
    float sq = s * s;
    sq += __shfl_xor(sq, 32, 64);              // pair the wave's 2 k's
    if ((t & 63) < 32) wpart[t >> 6][t & 31] = sq;
    __syncthreads();
    float n2 = 0.f;
    #pragma unroll
    for (int ww = 0; ww < 8; ++ww) n2 += wpart[ww][t & 31];   // over 16 k
    float v = n2 / (1.f + n2) * rsqrtf(n2 + 1e-7f) * s;
    if (PHASE == 2)
        out[(size_t)b * 512 + (t & 31) * 16 + (t >> 5)] = v;  // [b][o][k]
    else if (PHASE == 1)
        vsum[(size_t)b * 512 + t] += v;
    else
        vsum[(size_t)b * 512 + t] = v;
}

// ---------------------------------------------------------------------------
extern "C" void kernel_launch(void* const* d_in, const int* in_sizes, int n_in,
                              void* d_out, int out_size, void* d_ws, size_t ws_size,
                              hipStream_t stream)
{
    const float* x = (const float*)d_in[0];
    const float* W = (const float*)d_in[1];
    float* out = (float*)d_out;
    char* ws = (char*)d_ws;

    const size_t partB  = (size_t)64 * 256 * 512 * 4;  // 32 MB
    const size_t part2B = (size_t)64 * 4 * 512 * 4;    // 512 KB
    const size_t vsumB  = (size_t)64 * 512 * 4;        // 128 KB
    if (ws_size < partB + part2B + vsumB) return;      // 32.625 MB (proven ok)

    float* part  = (float*)ws;
    float* part2 = (float*)(ws + partB);
    float* vsum  = (float*)(ws + partB + part2B);

    // round 0: c uniform -> v0; vsum = v0
    pass_kernel<1><<<512, 512, 0, stream>>>(x, W, vsum, part);
    reduce1<<<256, 128, 0, stream>>>(part, part2);
    reduce2<0><<<64, 512, 0, stream>>>(part2, vsum, out);
    // round 1: logits = u_hat . v0 -> v1; vsum = v0 + v1
    pass_kernel<0><<<512, 512, 0, stream>>>(x, W, vsum, part);
    reduce1<<<256, 128, 0, stream>>>(part, part2);
    reduce2<1><<<64, 512, 0, stream>>>(part2, vsum, out);
    // round 2: logits = u_hat . (v0+v1) -> v2 = output
    pass_kernel<0><<<512, 512, 0, stream>>>(x, W, vsum, part);
    reduce1<<<256, 128, 0, stream>>>(part, part2);
    reduce2<2><<<64, 512, 0, stream>>>(part2, vsum, out);
}